// Round 5
// baseline (572.844 us; speedup 1.0000x reference)
//
#include <hip/hip_runtime.h>
#include <stdint.h>

#define T_TOK 16384
#define D_DIM 4096
#define E_EXP 128
#define TE ((size_t)T_TOK * E_EXP)

#define TAU 3e-4f
#define FLAG_CAP 8192
#define WT_OFF 65536
#define WT_ELEMS ((size_t)E_EXP * D_DIM)   // 524288 shorts per array

#define NSPLIT 4
#define KLEN (D_DIM / NSPLIT)              // 1024
#define ITERS (KLEN / 32)                  // 32

typedef __attribute__((ext_vector_type(8))) short short8;
typedef __attribute__((ext_vector_type(4))) float f32x4;

// ---------------- Threefry-2x32 (JAX-compatible) ----------------
#define TF_ROUND(x0, x1, r) { x0 += x1; x1 = (x1 << r) | (x1 >> (32 - r)); x1 ^= x0; }

__host__ __device__ inline void tf2x32(uint32_t k0, uint32_t k1, uint32_t x0, uint32_t x1,
                                       uint32_t* o0, uint32_t* o1) {
  uint32_t ks2 = k0 ^ k1 ^ 0x1BD11BDAu;
  x0 += k0; x1 += k1;
  TF_ROUND(x0, x1, 13) TF_ROUND(x0, x1, 15) TF_ROUND(x0, x1, 26) TF_ROUND(x0, x1, 6)
  x0 += k1; x1 += ks2 + 1u;
  TF_ROUND(x0, x1, 17) TF_ROUND(x0, x1, 29) TF_ROUND(x0, x1, 16) TF_ROUND(x0, x1, 24)
  x0 += ks2; x1 += k0 + 2u;
  TF_ROUND(x0, x1, 13) TF_ROUND(x0, x1, 15) TF_ROUND(x0, x1, 26) TF_ROUND(x0, x1, 6)
  x0 += k0; x1 += k1 + 3u;
  TF_ROUND(x0, x1, 17) TF_ROUND(x0, x1, 29) TF_ROUND(x0, x1, 16) TF_ROUND(x0, x1, 24)
  x0 += k1; x1 += ks2 + 4u;
  TF_ROUND(x0, x1, 13) TF_ROUND(x0, x1, 15) TF_ROUND(x0, x1, 26) TF_ROUND(x0, x1, 6)
  x0 += ks2; x1 += k0 + 5u;
  *o0 = x0; *o1 = x1;
}

__device__ inline uint32_t rng_bits(uint32_t j, uint32_t fk0, uint32_t fk1) {
  uint32_t o0, o1;
  tf2x32(fk0, fk1, 0u, j, &o0, &o1);
  return o0 ^ o1;
}

__device__ inline float gumbel_f32(uint32_t j, uint32_t fk0, uint32_t fk1) {
  uint32_t bits = rng_bits(j, fk0, fk1);
  float f = __uint_as_float((bits >> 9) | 0x3f800000u) - 1.0f;
  const float mn = 1e-6f;
  const float mx = (float)(1.0 - 1e-6);
  float u = fmaxf(mn, f * (mx - mn) + mn);
  return -logf(-logf(u));
}

__device__ inline double gumbel_f64(uint32_t j, uint32_t fk0, uint32_t fk1) {
  uint32_t bits = rng_bits(j, fk0, fk1);
  float f = __uint_as_float((bits >> 9) | 0x3f800000u) - 1.0f;
  const float mn = 1e-6f;
  const float mx = (float)(1.0 - 1e-6);
  float u = fmaxf(mn, f * (mx - mn) + mn);
  return -log(-log((double)u));
}

// ---------------- bf16 split helpers ----------------
__device__ inline unsigned short f2bf(float x) {        // round-nearest-even
  uint32_t u = __float_as_uint(x);
  return (unsigned short)((u + 0x7fffu + ((u >> 16) & 1u)) >> 16);
}
__device__ inline float bf2f(unsigned short h) { return __uint_as_float(((uint32_t)h) << 16); }

// ---------------- prep: W[k][e] -> fragment-order bf16 hi/lo ----------------
// Slot (kb 0..127, cg 0..7, ln 0..63) holds W[kb*32 + (ln>>4)*8 + j][cg*16 + (ln&15)],
// j=0..7, at linear short offset slot*8. Exactly MFMA B-fragment order: the GEMM loads
// each fragment as one coalesced 16B/lane global read. No LDS anywhere.
__global__ __launch_bounds__(256) void prep_kernel(const float* __restrict__ W,
                                                   unsigned short* __restrict__ WFhi,
                                                   unsigned short* __restrict__ WFlo,
                                                   int* __restrict__ wsi) {
  if (blockIdx.x == 0 && threadIdx.x < 16) wsi[threadIdx.x] = 0;
  const int gslot = blockIdx.x * 256 + threadIdx.x;   // 0..65535
  const int kb  = gslot >> 9;
  const int rem = gslot & 511;
  const int cg  = rem >> 6;
  const int ln  = rem & 63;
  const int q = ln >> 4, m = ln & 15;
  const int e  = cg * 16 + m;
  const int k0 = kb * 32 + q * 8;

  __attribute__((aligned(16))) unsigned short hi[8];
  __attribute__((aligned(16))) unsigned short lo[8];
  #pragma unroll
  for (int j = 0; j < 8; j++) {
    float w = W[(size_t)(k0 + j) * E_EXP + e];
    unsigned short h16 = f2bf(w);
    hi[j] = h16;
    lo[j] = f2bf(w - bf2f(h16));
  }
  *(uint4*)(WFhi + (size_t)gslot * 8) = *(const uint4*)hi;
  *(uint4*)(WFlo + (size_t)gslot * 8) = *(const uint4*)lo;
}

// ---------------- barrier-free register GEMM ----------------
// grid (T/128, NSPLIT), 256 thr = 4 waves. Wave owns 32 token-rows (2 A-frags) x all
// 128 experts. A: direct global->reg in fragment order, split to bf16 hi/lo in-register,
// prefetched one K32-iteration ahead (MFMA burst covers HBM latency). B: direct global
// fragment loads from WFhi/WFlo (L2-resident). Zero LDS, zero barriers.
__global__ __launch_bounds__(256, 2) void gemm_direct(const float* __restrict__ h,
                                                      const unsigned short* __restrict__ WFhi,
                                                      const unsigned short* __restrict__ WFlo,
                                                      float* __restrict__ outbase) {
  const int tid  = threadIdx.x;
  const int ln   = tid & 63;
  const int wv   = tid >> 6;
  const int m    = ln & 15;
  const int quad = ln >> 4;
  const int t0   = blockIdx.x * 128 + wv * 32;
  const int kbase = blockIdx.y * KLEN;
  const int kb0   = kbase >> 5;           // starting K32-chunk index

  const float* ar0 = h + (size_t)(t0 + m) * D_DIM + kbase + quad * 8;
  const float* ar1 = ar0 + (size_t)16 * D_DIM;

  f32x4 acc[2][8];
  #pragma unroll
  for (int r = 0; r < 2; r++)
    #pragma unroll
    for (int c = 0; c < 8; c++) acc[r][c] = (f32x4){0.f, 0.f, 0.f, 0.f};

  // prefetch iter 0
  float4 pa0 = *(const float4*)(ar0);
  float4 pa1 = *(const float4*)(ar0 + 4);
  float4 pa2 = *(const float4*)(ar1);
  float4 pa3 = *(const float4*)(ar1 + 4);

  for (int it = 0; it < ITERS; ++it) {
    // split current A to bf16 hi/lo (registers only)
    float v[2][8] = {{pa0.x, pa0.y, pa0.z, pa0.w, pa1.x, pa1.y, pa1.z, pa1.w},
                     {pa2.x, pa2.y, pa2.z, pa2.w, pa3.x, pa3.y, pa3.z, pa3.w}};
    short8 ahi[2], alo[2];
    #pragma unroll
    for (int r = 0; r < 2; r++)
      #pragma unroll
      for (int j = 0; j < 8; j++) {
        unsigned short t16 = f2bf(v[r][j]);
        ahi[r][j] = (short)t16;
        alo[r][j] = (short)f2bf(v[r][j] - bf2f(t16));
      }

    // prefetch next iteration's A (issued before the MFMA burst)
    const int itn = (it + 1 < ITERS) ? it + 1 : it;
    pa0 = *(const float4*)(ar0 + itn * 32);
    pa1 = *(const float4*)(ar0 + itn * 32 + 4);
    pa2 = *(const float4*)(ar1 + itn * 32);
    pa3 = *(const float4*)(ar1 + itn * 32 + 4);

    // B fragment base for this K32 chunk
    const size_t bofs = ((size_t)(kb0 + it) * 8) * 512 + (size_t)ln * 8;
    const unsigned short* bh = WFhi + bofs;
    const unsigned short* bl = WFlo + bofs;

    #pragma unroll
    for (int c = 0; c < 8; c++) {
      short8 bhi = *(const short8*)(bh + c * 512);
      short8 blo = *(const short8*)(bl + c * 512);
      #pragma unroll
      for (int r = 0; r < 2; r++) {
        acc[r][c] = __builtin_amdgcn_mfma_f32_16x16x32_bf16(ahi[r], bhi, acc[r][c], 0, 0, 0);
        acc[r][c] = __builtin_amdgcn_mfma_f32_16x16x32_bf16(ahi[r], blo, acc[r][c], 0, 0, 0);
        acc[r][c] = __builtin_amdgcn_mfma_f32_16x16x32_bf16(alo[r], bhi, acc[r][c], 0, 0, 0);
      }
    }
  }

  // partial for split s -> output region s (route re-reads + overwrites; 8.4 MB each)
  float* ob = outbase + (size_t)blockIdx.y * TE;
  #pragma unroll
  for (int r = 0; r < 2; r++)
    #pragma unroll
    for (int reg = 0; reg < 4; reg++) {
      const size_t row = (size_t)(t0 + r * 16 + quad * 4 + reg) * E_EXP;
      #pragma unroll
      for (int c = 0; c < 8; c++)
        ob[row + c * 16 + m] = acc[r][c][reg];
    }
}

// ---------------- wave helpers ----------------
__device__ inline uint32_t ordkey(float v) {
  uint32_t b = __float_as_uint(v);
  return (b & 0x80000000u) ? ~b : (b | 0x80000000u);
}
__device__ inline float inv_ordkey(uint32_t k) {
  return (k & 0x80000000u) ? __uint_as_float(k & 0x7fffffffu) : __uint_as_float(~k);
}
__device__ inline unsigned long long wave_max_u64(unsigned long long v) {
  #pragma unroll
  for (int off = 32; off > 0; off >>= 1) {
    unsigned long long o = __shfl_xor(v, off, 64);
    v = (o > v) ? o : v;
  }
  return v;
}
__device__ inline float wave_max_f32(float v) {
  #pragma unroll
  for (int off = 32; off > 0; off >>= 1) v = fmaxf(v, __shfl_xor(v, off, 64));
  return v;
}
__device__ inline float wave_sum_f32(float v) {
  #pragma unroll
  for (int off = 32; off > 0; off >>= 1) v += __shfl_xor(v, off, 64);
  return v;
}
__device__ inline double wave_sum_f64(double v) {
  #pragma unroll
  for (int off = 32; off > 0; off >>= 1) v += __shfl_xor(v, off, 64);
  return v;
}

// ---------------- route: sum partials (in-place in out regions), f32 fast path ----------------
__global__ __launch_bounds__(256) void route_kernel(float* out,
                                                    int* flag_cnt, int* flags,
                                                    uint32_t fk0, uint32_t fk1) {
  const int lane = threadIdx.x & 63;
  const int t = blockIdx.x * 4 + (threadIdx.x >> 6);
  const size_t base = (size_t)t * E_EXP;
  float* mask_o   = out;
  float* probs_o  = out + TE;
  float* lclean_o = out + 2 * TE;
  float* lsel_o   = out + 3 * TE;

  double a0 = 0.0, a1 = 0.0;
  #pragma unroll
  for (int s = 0; s < NSPLIT; s++) {
    a0 += (double)out[(size_t)s * TE + base + lane];
    a1 += (double)out[(size_t)s * TE + base + lane + 64];
  }
  const float lc0 = (float)a0, lc1 = (float)a1;

  const float ls0 = lc0 + gumbel_f32((uint32_t)(base + lane), fk0, fk1);
  const float ls1 = lc1 + gumbel_f32((uint32_t)(base + lane + 64), fk0, fk1);

  unsigned long long pk0 = (((unsigned long long)ordkey(ls0)) << 32) | (unsigned)(127 - lane);
  unsigned long long pk1 = (((unsigned long long)ordkey(ls1)) << 32) | (unsigned)(63 - lane);
  bool sel0 = false, sel1 = false;
  unsigned long long m8 = 0;
  #pragma unroll
  for (int it = 0; it < 8; ++it) {
    unsigned long long c0 = sel0 ? 0ull : pk0;
    unsigned long long c1 = sel1 ? 0ull : pk1;
    m8 = wave_max_u64(c0 > c1 ? c0 : c1);
    int ew = 127 - (int)(m8 & 0xffull);
    if (ew == lane)      sel0 = true;
    if (ew == lane + 64) sel1 = true;
  }
  unsigned long long c0 = sel0 ? 0ull : pk0;
  unsigned long long c1 = sel1 ? 0ull : pk1;
  unsigned long long m9 = wave_max_u64(c0 > c1 ? c0 : c1);
  float gap = inv_ordkey((uint32_t)(m8 >> 32)) - inv_ordkey((uint32_t)(m9 >> 32));

  float mx = wave_max_f32(fmaxf(lc0, lc1));
  float p0 = __expf(lc0 - mx);
  float p1 = __expf(lc1 - mx);
  float s8 = wave_sum_f32((sel0 ? p0 : 0.f) + (sel1 ? p1 : 0.f));

  lclean_o[base + lane]       = lc0;
  lclean_o[base + lane + 64]  = lc1;
  lsel_o[base + lane]         = ls0;
  lsel_o[base + lane + 64]    = ls1;
  mask_o[base + lane]         = sel0 ? 1.0f : 0.0f;
  mask_o[base + lane + 64]    = sel1 ? 1.0f : 0.0f;
  probs_o[base + lane]        = sel0 ? (p0 / s8) : 0.0f;
  probs_o[base + lane + 64]   = sel1 ? (p1 / s8) : 0.0f;

  if (lane == 0 && gap < TAU) {
    int idx = atomicAdd(flag_cnt, 1);
    if (idx < FLAG_CAP) flags[idx] = t;
  }
}

// ---------------- fp64 recompute of flagged tokens (8-way ILP) ----------------
__global__ __launch_bounds__(256) void recompute_kernel(const float* __restrict__ h,
                                                        const float* __restrict__ W,
                                                        const int* __restrict__ flag_cnt,
                                                        const int* __restrict__ flags,
                                                        float* __restrict__ mask_out,
                                                        float* __restrict__ probs_out,
                                                        float* __restrict__ lclean_out,
                                                        float* __restrict__ lsel_out,
                                                        uint32_t fk0, uint32_t fk1) {
  __shared__ __align__(16) float shf[D_DIM];
  __shared__ double dsum[E_EXP];
  __shared__ float larr[E_EXP];
  const int tid = threadIdx.x;
  int cnt = *flag_cnt;
  if (cnt > FLAG_CAP) cnt = FLAG_CAP;

  for (int ii = blockIdx.x; ii < cnt; ii += gridDim.x) {
    const int t = flags[ii];
    #pragma unroll
    for (int s = 0; s < 4; s++) {
      int f4 = s * 256 + tid;
      *(float4*)&shf[f4 * 4] = *(const float4*)(h + (size_t)t * D_DIM + f4 * 4);
    }
    __syncthreads();

    const int e = tid & 127;
    const int half = tid >> 7;
    const int kb = half * (D_DIM / 2);
    double acc[8];
    #pragma unroll
    for (int j = 0; j < 8; j++) acc[j] = 0.0;
    #pragma unroll 2
    for (int k = 0; k < D_DIM / 2; k += 8) {
      #pragma unroll
      for (int j = 0; j < 8; j++) {
        int kk = kb + k + j;
        acc[j] = fma((double)shf[kk], (double)W[(size_t)kk * E_EXP + e], acc[j]);
      }
    }
    double a = ((acc[0] + acc[1]) + (acc[2] + acc[3])) + ((acc[4] + acc[5]) + (acc[6] + acc[7]));
    if (half == 1) dsum[e] = a;
    __syncthreads();
    if (half == 0) {
      float lc = (float)(a + dsum[e]);
      larr[e] = lc;
      lclean_out[(size_t)t * E_EXP + e] = lc;
    }
    __syncthreads();

    if (tid < 64) {
      const size_t base = (size_t)t * E_EXP;
      const int lane = tid;
      float lc0 = larr[lane], lc1 = larr[lane + 64];
      float ls0 = lc0 + (float)gumbel_f64((uint32_t)(base + lane), fk0, fk1);
      float ls1 = lc1 + (float)gumbel_f64((uint32_t)(base + lane + 64), fk0, fk1);
      lsel_out[base + lane]      = ls0;
      lsel_out[base + lane + 64] = ls1;

      unsigned long long pk0 = (((unsigned long long)ordkey(ls0)) << 32) | (unsigned)(127 - lane);
      unsigned long long pk1 = (((unsigned long long)ordkey(ls1)) << 32) | (unsigned)(63 - lane);
      bool sel0 = false, sel1 = false;
      #pragma unroll
      for (int it = 0; it < 8; ++it) {
        unsigned long long cc0 = sel0 ? 0ull : pk0;
        unsigned long long cc1 = sel1 ? 0ull : pk1;
        unsigned long long mm = wave_max_u64(cc0 > cc1 ? cc0 : cc1);
        int ew = 127 - (int)(mm & 0xffull);
        if (ew == lane)      sel0 = true;
        if (ew == lane + 64) sel1 = true;
      }
      float mx = wave_max_f32(fmaxf(lc0, lc1));
      double pd0 = exp((double)lc0 - (double)mx);
      double pd1 = exp((double)lc1 - (double)mx);
      double s8 = wave_sum_f64((sel0 ? pd0 : 0.0) + (sel1 ? pd1 : 0.0));

      mask_out[base + lane]       = sel0 ? 1.0f : 0.0f;
      mask_out[base + lane + 64]  = sel1 ? 1.0f : 0.0f;
      probs_out[base + lane]      = sel0 ? (float)(pd0 / s8) : 0.0f;
      probs_out[base + lane + 64] = sel1 ? (float)(pd1 / s8) : 0.0f;
    }
    __syncthreads();
  }
}

extern "C" void kernel_launch(void* const* d_in, const int* in_sizes, int n_in,
                              void* d_out, int out_size, void* d_ws, size_t ws_size,
                              hipStream_t stream) {
  const float* h = (const float*)d_in[0];
  const float* W = (const float*)d_in[1];

  float* out      = (float*)d_out;
  float* mask_o   = out;
  float* probs_o  = out + TE;
  float* lclean_o = out + 2 * TE;
  float* lsel_o   = out + 3 * TE;

  int* wsi   = (int*)d_ws;
  int* flags = wsi + 16;
  unsigned short* WFhi = (unsigned short*)((char*)d_ws + WT_OFF);
  unsigned short* WFlo = WFhi + WT_ELEMS;

  uint32_t fk0, fk1;
  tf2x32(0u, 7u, 0u, 1u, &fk0, &fk1);

  prep_kernel<<<256, 256, 0, stream>>>(W, WFhi, WFlo, wsi);
  gemm_direct<<<dim3(T_TOK / 128, NSPLIT), 256, 0, stream>>>(h, WFhi, WFlo, out);
  route_kernel<<<T_TOK / 4, 256, 0, stream>>>(out, wsi, flags, fk0, fk1);
  recompute_kernel<<<256, 256, 0, stream>>>(h, W, wsi, flags, mask_o, probs_o, lclean_o, lsel_o,
                                            fk0, fk1);
}